// Round 7
// baseline (69.942 us; speedup 1.0000x reference)
//
#include <hip/hip_runtime.h>

#define Bc 64
#define Sc 512
#define Dc 768
#define NLc 9
#define Lc 11
#define START (Lc-2)
#define ENDL (Lc-1)
#define NEGC -10000.0f
#define LOG2E 1.4426950408889634f
#define LN2 0.6931471805599453f
#define CHUNK 16
#define NCH (Sc / CHUNK)   // 32
#define R4F (Dc / 4)       // 192 float4 per row

// K1: logits[b,s,l] = dot(inputs[b,s,:], W[l,:]) + bias[l]
// Full-row-per-wave: block = 32 contiguous rows, wave = 8 contiguous rows,
// pass = 2 rows. Every global load is 1 KB CONTIGUOUS (64 lanes x float4 of
// one row); wave streams 24 KB contiguous (R6 post-mortem: 4x256B scattered
// segments held us at 2 TB/s). W staged in LDS; 9 b128 reads per chunk feed
// both rows. 6-level butterfly reduce (1,2,4,8 DPP; 16,32 LDS-pipe). Depth-1
// pass prefetch with NAMED float4 only; (256,4) cap 128, ~95 live, no spill.
__global__ __launch_bounds__(256, 4) void k_logits(const float* __restrict__ x,
    const float* __restrict__ W, const float* __restrict__ bias,
    float* __restrict__ out)
{
  __shared__ float Wl[NLc * Dc];            // 27648 B
  {
    const float4* Wsrc = reinterpret_cast<const float4*>(W);
    float4* Wdst = reinterpret_cast<float4*>(Wl);
    for (int i = threadIdx.x; i < (NLc * Dc) / 4; i += 256) Wdst[i] = Wsrc[i];
  }
  __syncthreads();
  const int tid  = threadIdx.x;
  const int wid  = tid >> 6;
  const int lane = tid & 63;
  const int rbase = blockIdx.x * 32 + wid * 8;   // 8 contiguous rows per wave
  const float4* xb = reinterpret_cast<const float4*>(x);

  // per-lane store role (fixed): lanes 0-8 -> row even, 16-24 -> row odd
  const int idx = (lane < NLc) ? lane : ((lane >= 16 && lane < 16 + NLc) ? lane - 16 : -1);
  const float bsel = (idx >= 0) ? bias[idx] : 0.f;

  // prologue: pass-0 loads (rows rbase, rbase+1), 1 KB contiguous each
  size_t a = (size_t)rbase * R4F + lane;
  float4 cA0 = xb[a];           float4 cA1 = xb[a + 64];        float4 cA2 = xb[a + 128];
  float4 cB0 = xb[a + R4F];     float4 cB1 = xb[a + R4F + 64];  float4 cB2 = xb[a + R4F + 128];

#pragma unroll
  for (int p = 0; p < 4; ++p) {
    float4 nA0, nA1, nA2, nB0, nB1, nB2;
    if (p < 3) {
      const size_t n = (size_t)(rbase + 2 * p + 2) * R4F + lane;
      nA0 = xb[n];          nA1 = xb[n + 64];        nA2 = xb[n + 128];
      nB0 = xb[n + R4F];    nB1 = xb[n + R4F + 64];  nB2 = xb[n + R4F + 128];
    }
    float accA[NLc], accB[NLc];
#pragma unroll
    for (int l = 0; l < NLc; l++) { accA[l] = 0.f; accB[l] = 0.f; }

#define CHUNK_FMA(XA, XB, JC)                                                  \
    {                                                                          \
      const float* wb = Wl + (JC)*256 + lane * 4;                              \
      _Pragma("unroll")                                                        \
      for (int l = 0; l < NLc; l++) {                                          \
        const float4 wv = *reinterpret_cast<const float4*>(wb + l * Dc);       \
        accA[l] = fmaf((XA).x, wv.x, accA[l]);                                 \
        accB[l] = fmaf((XB).x, wv.x, accB[l]);                                 \
        accA[l] = fmaf((XA).y, wv.y, accA[l]);                                 \
        accB[l] = fmaf((XB).y, wv.y, accB[l]);                                 \
        accA[l] = fmaf((XA).z, wv.z, accA[l]);                                 \
        accB[l] = fmaf((XB).z, wv.z, accB[l]);                                 \
        accA[l] = fmaf((XA).w, wv.w, accA[l]);                                 \
        accB[l] = fmaf((XB).w, wv.w, accB[l]);                                 \
      }                                                                        \
    }
    CHUNK_FMA(cA0, cB0, 0)
    CHUNK_FMA(cA1, cB1, 1)
    CHUNK_FMA(cA2, cB2, 2)
#undef CHUNK_FMA

    // 6-level butterfly across the full wave (row spans all 64 lanes)
#pragma unroll
    for (int off = 1; off <= 32; off <<= 1)
#pragma unroll
      for (int l = 0; l < NLc; l++) {
        accA[l] += __shfl_xor(accA[l], off);
        accB[l] += __shfl_xor(accB[l], off);
      }
    // select own label and store: lanes 0-8 row even, 16-24 row odd ->
    // the two 36 B stores are consecutive (72 B contiguous per pass)
    if (idx >= 0) {
      float sA = accA[0], sB = accB[0];
#pragma unroll
      for (int l = 1; l < NLc; l++) {
        sA = (idx == l) ? accA[l] : sA;
        sB = (idx == l) ? accB[l] : sB;
      }
      const int row = rbase + 2 * p + ((lane < 16) ? 0 : 1);
      const float v = ((lane < 16) ? sA : sB) + bsel;
      out[(size_t)row * NLc + idx] = v;
    }
    if (p < 3) { cA0 = nA0; cA1 = nA1; cA2 = nA2; cB0 = nB0; cB1 = nB1; cB2 = nB2; }
  }
}

// Phase 1: per (batch, chunk) compute the 11x11 log-semiring transfer matrix.
// Storage: Mout[(b*NCH+c)*121 + j*11 + i] = M[i][j] (exit i, enter j).
// Also zeroes the k_batch completion counter (block 0) each call.
__global__ __launch_bounds__(64) void k_chunk(const float* __restrict__ logits,
    const int* __restrict__ mask, const float* __restrict__ trans,
    float* __restrict__ Mout, unsigned* __restrict__ cnt)
{
  if (blockIdx.x == 0 && threadIdx.x == 0) cnt[0] = 0u;
  const int b = blockIdx.x / NCH;
  const int c = blockIdx.x % NCH;
  const int lane = threadIdx.x;
  __shared__ float Mbuf[2][121];
  __shared__ float Llog[CHUNK][NLc];

  int len = 0;
  for (int t = lane; t < Sc; t += 64) len += mask[b * Sc + t];
#pragma unroll
  for (int off = 32; off >= 1; off >>= 1) len += __shfl_xor(len, off);

  for (int i = lane; i < CHUNK * NLc; i += 64) {
    const int t = i / NLc, l = i % NLc;
    Llog[t][l] = logits[((size_t)b * Sc + c * CHUNK + t) * NLc + l];
  }
  for (int e = lane; e < 121; e += 64) {
    const int i = e % Lc, j = e / Lc;
    Mbuf[0][e] = (i == j) ? 0.f : NEGC;
  }
  const int e1 = lane;          const bool v1 = (e1 < 121);
  const int e2 = lane + 64;     const bool v2 = (e2 < 121);
  const int i1 = v1 ? (e1 % Lc) : 0, j1 = v1 ? (e1 / Lc) : 0;
  const int i2 = v2 ? (e2 % Lc) : 0, j2 = v2 ? (e2 / Lc) : 0;
  float trow1[Lc], trow2[Lc];
#pragma unroll
  for (int k = 0; k < Lc; k++) {
    trow1[k] = trans[i1 * Lc + k];
    trow2[k] = trans[i2 * Lc + k];
  }
  __syncthreads();

  int p = 0;
  for (int t = 0; t < CHUNK; ++t) {
    const int tg = c * CHUNK + t;
    if (tg < len) {   // uniform across block
      const float lg1 = (i1 < NLc) ? Llog[t][i1] : NEGC;
      const float lg2 = (i2 < NLc) ? Llog[t][i2] : NEGC;
      float terms[Lc];
      float m1 = -3.0e38f;
#pragma unroll
      for (int k = 0; k < Lc; k++) {
        terms[k] = trow1[k] + Mbuf[p][j1 * Lc + k];
        m1 = fmaxf(m1, terms[k]);
      }
      float s1 = 0.f;
#pragma unroll
      for (int k = 0; k < Lc; k++) s1 += exp2f((terms[k] - m1) * LOG2E);
      const float n1 = lg1 + m1 + log2f(s1) * LN2;
      float m2 = -3.0e38f;
#pragma unroll
      for (int k = 0; k < Lc; k++) {
        terms[k] = trow2[k] + Mbuf[p][j2 * Lc + k];
        m2 = fmaxf(m2, terms[k]);
      }
      float s2 = 0.f;
#pragma unroll
      for (int k = 0; k < Lc; k++) s2 += exp2f((terms[k] - m2) * LOG2E);
      const float n2 = lg2 + m2 + log2f(s2) * LN2;
      if (v1) Mbuf[p ^ 1][e1] = n1;
      if (v2) Mbuf[p ^ 1][e2] = n2;
      p ^= 1;
    }
    __syncthreads();
  }
  for (int e = lane; e < 121; e += 64)
    Mout[((size_t)b * NCH + c) * 121 + e] = Mbuf[p][e];
}

// K_batch: per batch -- wave 0 runs the 32-step combine (norm), waves 1-3 do
// unary+binary gathers concurrently; then part[b] = u - norm; the last block
// to finish sums all parts and writes the loss (agent-scope atomics, G16).
__global__ __launch_bounds__(256) void k_batch(const float* __restrict__ logits,
    const int* __restrict__ mask, const int* __restrict__ labels,
    const float* __restrict__ trans, const float* __restrict__ Min,
    float* __restrict__ part, unsigned* __restrict__ cnt,
    float* __restrict__ out)
{
  const int b = blockIdx.x;
  const int tid = threadIdx.x;
  const int wid = tid >> 6;
  const int lane = tid & 63;
  const int sl = lane & 15;
  __shared__ float Ms[NCH * 121];
  __shared__ int   ls[4];
  __shared__ float fs[4];
  __shared__ int   len_sh;
  __shared__ float norm_sh;
  __shared__ int   do_final;

  {
    const float4* src = reinterpret_cast<const float4*>(Min + (size_t)b * NCH * 121);
    for (int i = tid; i < (NCH * 121) / 4; i += 256)
      reinterpret_cast<float4*>(Ms)[i] = src[i];
  }
  int lp = 0;
  for (int t = tid; t < Sc; t += 256) lp += mask[b * Sc + t];
#pragma unroll
  for (int off = 32; off >= 1; off >>= 1) lp += __shfl_down(lp, off);
  if (lane == 0) ls[wid] = lp;
  __syncthreads();
  if (tid == 0) len_sh = ls[0] + ls[1] + ls[2] + ls[3];
  __syncthreads();
  const int len = len_sh;

  if (wid == 0) {
    const int ii = (sl < Lc) ? sl : 0;
    float alpha = (sl == START) ? 0.f : NEGC;
#pragma unroll 1
    for (int c = 0; c < NCH; ++c) {
      const float* M = Ms + c * 121;
      float terms[Lc];
      float m = -3.0e38f;
#pragma unroll
      for (int k = 0; k < Lc; k++) {
        const float ak = __shfl(alpha, k, 16);
        terms[k] = M[k * Lc + ii] + ak;
        m = fmaxf(m, terms[k]);
      }
      float s = 0.f;
#pragma unroll
      for (int k = 0; k < Lc; k++) s += exp2f((terms[k] - m) * LOG2E);
      const float anew = m + log2f(s) * LN2;
      alpha = (sl < Lc) ? anew : alpha;
    }
    float v = (sl < Lc) ? (alpha + trans[ENDL * Lc + sl]) : -3.0e38f;
    float mm = v;
#pragma unroll
    for (int off = 8; off >= 1; off >>= 1) mm = fmaxf(mm, __shfl_xor(mm, off, 16));
    float se = exp2f((v - mm) * LOG2E);
#pragma unroll
    for (int off = 8; off >= 1; off >>= 1) se += __shfl_xor(se, off, 16);
    if (lane == 0) norm_sh = mm + log2f(se) * LN2;
  } else {
    float u = 0.f;
    for (int t = tid - 64; t < Sc; t += 192)
      if (t < len) u += logits[((size_t)b * Sc + t) * NLc + labels[b * Sc + t]];
    for (int t = tid - 64; t <= Sc; t += 192) {
      if (t <= len) {
        const int cur = (t == 0) ? START : ((t - 1 < len) ? labels[b * Sc + t - 1] : ENDL);
        const int nxt = (t < len) ? labels[b * Sc + t] : ENDL;
        u += trans[nxt * Lc + cur];
      }
    }
#pragma unroll
    for (int off = 32; off >= 1; off >>= 1) u += __shfl_down(u, off);
    if (lane == 0) fs[wid] = u;
  }
  __syncthreads();

  if (tid == 0) {
    const float pb = fs[1] + fs[2] + fs[3] - norm_sh;
    __hip_atomic_store(&part[b], pb, __ATOMIC_RELEASE, __HIP_MEMORY_SCOPE_AGENT);
    const unsigned old = __hip_atomic_fetch_add(cnt, 1u, __ATOMIC_ACQ_REL,
                                                __HIP_MEMORY_SCOPE_AGENT);
    do_final = (old == (unsigned)(Bc - 1)) ? 1 : 0;
  }
  __syncthreads();
  if (do_final && wid == 0) {
    float v = __hip_atomic_load(&part[lane], __ATOMIC_RELAXED,
                                __HIP_MEMORY_SCOPE_AGENT);
#pragma unroll
    for (int off = 32; off >= 1; off >>= 1) v += __shfl_xor(v, off);
    if (lane == 0) out[0] = -v * (1.0f / Bc);
  }
}

extern "C" void kernel_launch(void* const* d_in, const int* in_sizes, int n_in,
                              void* d_out, int out_size, void* d_ws, size_t ws_size,
                              hipStream_t stream)
{
  const float* x      = (const float*)d_in[0];
  const int*   mask   = (const int*)d_in[1];
  const int*   labels = (const int*)d_in[2];
  const float* W      = (const float*)d_in[3];
  const float* bias   = (const float*)d_in[4];
  const float* trans  = (const float*)d_in[5];
  float* out = (float*)d_out;
  float* ws  = (float*)d_ws;

  float*    ws_logits = ws;                                  // B*S*NL floats
  float*    ws_M      = ws_logits + (size_t)Bc * Sc * NLc;   // B*NCH*121 floats
  float*    ws_part   = ws_M + (size_t)Bc * NCH * 121;       // B floats
  unsigned* ws_cnt    = (unsigned*)(ws_part + Bc);           // 1 uint

  hipLaunchKernelGGL(k_logits, dim3(1024), dim3(256), 0, stream, x, W, bias, ws_logits);
  hipLaunchKernelGGL(k_chunk,  dim3(Bc * NCH), dim3(64), 0, stream, ws_logits, mask, trans, ws_M, ws_cnt);
  hipLaunchKernelGGL(k_batch,  dim3(Bc), dim3(256), 0, stream, ws_logits, mask, labels, trans, ws_M, ws_part, ws_cnt, out);
}

// Round 8
// 63.925 us; speedup vs baseline: 1.0941x; 1.0941x over previous
//
#include <hip/hip_runtime.h>

#define Bc 64
#define Sc 512
#define Dc 768
#define NLc 9
#define Lc 11
#define START (Lc-2)
#define ENDL (Lc-1)
#define NEGC -10000.0f
#define LOG2E 1.4426950408889634f
#define LN2 0.6931471805599453f
#define CHUNK 16
#define NCH (Sc / CHUNK)   // 32
#define WROW 776           // padded bf16 row stride (768 + 8): byte stride 1552 -> +4 banks/row

typedef __attribute__((ext_vector_type(8))) short s16x8;   // 8 bf16 (4 VGPRs)
typedef __attribute__((ext_vector_type(4))) float f32x4;   // 4 fp32 acc

union U4 { float4 f; unsigned int u[4]; };
union R8 { unsigned int w[4]; s16x8 v; };

// pack 8 fp32 (lo=k..k+3, hi=k+4..k+7) -> 8 bf16 (truncation; bias ~2^-10 rel, fine vs thr=24)
static __device__ __forceinline__ s16x8 pack8(float4 lo, float4 hi) {
  U4 L, H; L.f = lo; H.f = hi;
  R8 r;
  r.w[0] = (L.u[1] & 0xFFFF0000u) | (L.u[0] >> 16);
  r.w[1] = (L.u[3] & 0xFFFF0000u) | (L.u[2] >> 16);
  r.w[2] = (H.u[1] & 0xFFFF0000u) | (H.u[0] >> 16);
  r.w[3] = (H.u[3] & 0xFFFF0000u) | (H.u[2] >> 16);
  return r.v;
}

// K1 (MFMA): logits[b,s,l] = dot(x[row,:], W[l,:]) + b[l]  via bf16 mfma_16x16x32.
// R7 post-mortem: all VALU schedules are issue-bound (~864 FMA + 108 b128/lane);
// MFMA removes that stream. Wave = one 16-row tile, 24 unrolled MFMAs over K.
// A-frag: lane l = row (l&15), k = (l>>4)*8+e -> 2 float4 global loads, bit-pack.
// B-frag (W^T): lane l = label (l&15), same k -> 1 ds_read_b128 from padded LDS.
// C/D (m89-verified): col(label) = l&15, row = (l>>4)*4 + reg.
__global__ __launch_bounds__(256, 4) void k_logits(const float* __restrict__ x,
    const float* __restrict__ W, const float* __restrict__ bias,
    float* __restrict__ out)
{
  __shared__ unsigned short Wb[16][WROW];   // 24832 B, rows 9..15 zero
  for (int i = threadIdx.x; i < 16 * 384; i += 256) {
    const int r = i / 384, c = i % 384;     // c = u32 word (2 bf16)
    unsigned int w = 0u;
    if (r < NLc) {
      U4 t; t.f.x = W[r * Dc + 2 * c]; t.f.y = W[r * Dc + 2 * c + 1];
      w = (t.u[1] & 0xFFFF0000u) | (t.u[0] >> 16);
    }
    *reinterpret_cast<unsigned int*>(&Wb[r][2 * c]) = w;
  }
  __syncthreads();

  const int lane = threadIdx.x & 63;
  const int wid  = threadIdx.x >> 6;
  const int tile = blockIdx.x * 4 + wid;    // 2048 tiles of 16 rows
  const int R    = tile * 16;
  const int j    = lane & 15;               // label (B col) / A row
  const int kg   = lane >> 4;               // k-group 0..3

  const float* xp = x + (size_t)(R + j) * Dc + kg * 8;
  const unsigned short* wrow = &Wb[j][kg * 8];

  f32x4 acc = {0.f, 0.f, 0.f, 0.f};
  // depth-2 prefetch, named scalars (R5 lesson: arrays -> scratch)
  float4 a0 = *reinterpret_cast<const float4*>(xp);
  float4 a1 = *reinterpret_cast<const float4*>(xp + 4);
  float4 b0 = *reinterpret_cast<const float4*>(xp + 32);
  float4 b1 = *reinterpret_cast<const float4*>(xp + 36);

#pragma unroll
  for (int t = 0; t < 24; ++t) {
    float4 n0, n1;
    if (t < 22) {
      n0 = *reinterpret_cast<const float4*>(xp + 32 * (t + 2));
      n1 = *reinterpret_cast<const float4*>(xp + 32 * (t + 2) + 4);
    }
    const s16x8 afrag = pack8(a0, a1);
    const s16x8 bfrag = *reinterpret_cast<const s16x8*>(wrow + 32 * t);
    acc = __builtin_amdgcn_mfma_f32_16x16x32_bf16(afrag, bfrag, acc, 0, 0, 0);
    a0 = b0; a1 = b1;
    if (t < 22) { b0 = n0; b1 = n1; }
  }

  if (j < NLc) {
    const float bb = bias[j];
#pragma unroll
    for (int r = 0; r < 4; ++r) {
      const int row = R + kg * 4 + r;
      out[(size_t)row * NLc + j] = acc[r] + bb;
    }
  }
}

// Phase 1: per (batch, chunk) compute the 11x11 log-semiring transfer matrix.
// Storage: Mout[(b*NCH+c)*121 + j*11 + i] = M[i][j] (exit i, enter j).
// Also zeroes the k_batch completion counter (block 0) each call.
__global__ __launch_bounds__(64) void k_chunk(const float* __restrict__ logits,
    const int* __restrict__ mask, const float* __restrict__ trans,
    float* __restrict__ Mout, unsigned* __restrict__ cnt)
{
  if (blockIdx.x == 0 && threadIdx.x == 0) cnt[0] = 0u;
  const int b = blockIdx.x / NCH;
  const int c = blockIdx.x % NCH;
  const int lane = threadIdx.x;
  __shared__ float Mbuf[2][121];
  __shared__ float Llog[CHUNK][NLc];

  int len = 0;
  for (int t = lane; t < Sc; t += 64) len += mask[b * Sc + t];
#pragma unroll
  for (int off = 32; off >= 1; off >>= 1) len += __shfl_xor(len, off);

  for (int i = lane; i < CHUNK * NLc; i += 64) {
    const int t = i / NLc, l = i % NLc;
    Llog[t][l] = logits[((size_t)b * Sc + c * CHUNK + t) * NLc + l];
  }
  for (int e = lane; e < 121; e += 64) {
    const int i = e % Lc, j = e / Lc;
    Mbuf[0][e] = (i == j) ? 0.f : NEGC;
  }
  const int e1 = lane;          const bool v1 = (e1 < 121);
  const int e2 = lane + 64;     const bool v2 = (e2 < 121);
  const int i1 = v1 ? (e1 % Lc) : 0, j1 = v1 ? (e1 / Lc) : 0;
  const int i2 = v2 ? (e2 % Lc) : 0, j2 = v2 ? (e2 / Lc) : 0;
  float trow1[Lc], trow2[Lc];
#pragma unroll
  for (int k = 0; k < Lc; k++) {
    trow1[k] = trans[i1 * Lc + k];
    trow2[k] = trans[i2 * Lc + k];
  }
  __syncthreads();

  int p = 0;
  for (int t = 0; t < CHUNK; ++t) {
    const int tg = c * CHUNK + t;
    if (tg < len) {   // uniform across block
      const float lg1 = (i1 < NLc) ? Llog[t][i1] : NEGC;
      const float lg2 = (i2 < NLc) ? Llog[t][i2] : NEGC;
      float terms[Lc];
      float m1 = -3.0e38f;
#pragma unroll
      for (int k = 0; k < Lc; k++) {
        terms[k] = trow1[k] + Mbuf[p][j1 * Lc + k];
        m1 = fmaxf(m1, terms[k]);
      }
      float s1 = 0.f;
#pragma unroll
      for (int k = 0; k < Lc; k++) s1 += exp2f((terms[k] - m1) * LOG2E);
      const float n1 = lg1 + m1 + log2f(s1) * LN2;
      float m2 = -3.0e38f;
#pragma unroll
      for (int k = 0; k < Lc; k++) {
        terms[k] = trow2[k] + Mbuf[p][j2 * Lc + k];
        m2 = fmaxf(m2, terms[k]);
      }
      float s2 = 0.f;
#pragma unroll
      for (int k = 0; k < Lc; k++) s2 += exp2f((terms[k] - m2) * LOG2E);
      const float n2 = lg2 + m2 + log2f(s2) * LN2;
      if (v1) Mbuf[p ^ 1][e1] = n1;
      if (v2) Mbuf[p ^ 1][e2] = n2;
      p ^= 1;
    }
    __syncthreads();
  }
  for (int e = lane; e < 121; e += 64)
    Mout[((size_t)b * NCH + c) * 121 + e] = Mbuf[p][e];
}

// K_batch: per batch -- wave 0 runs the 32-step combine (norm), waves 1-3 do
// unary+binary gathers concurrently; then part[b] = u - norm; the last block
// to finish sums all parts and writes the loss (agent-scope atomics, G16).
__global__ __launch_bounds__(256) void k_batch(const float* __restrict__ logits,
    const int* __restrict__ mask, const int* __restrict__ labels,
    const float* __restrict__ trans, const float* __restrict__ Min,
    float* __restrict__ part, unsigned* __restrict__ cnt,
    float* __restrict__ out)
{
  const int b = blockIdx.x;
  const int tid = threadIdx.x;
  const int wid = tid >> 6;
  const int lane = tid & 63;
  const int sl = lane & 15;
  __shared__ float Ms[NCH * 121];
  __shared__ int   ls[4];
  __shared__ float fs[4];
  __shared__ int   len_sh;
  __shared__ float norm_sh;
  __shared__ int   do_final;

  {
    const float4* src = reinterpret_cast<const float4*>(Min + (size_t)b * NCH * 121);
    for (int i = tid; i < (NCH * 121) / 4; i += 256)
      reinterpret_cast<float4*>(Ms)[i] = src[i];
  }
  int lp = 0;
  for (int t = tid; t < Sc; t += 256) lp += mask[b * Sc + t];
#pragma unroll
  for (int off = 32; off >= 1; off >>= 1) lp += __shfl_down(lp, off);
  if (lane == 0) ls[wid] = lp;
  __syncthreads();
  if (tid == 0) len_sh = ls[0] + ls[1] + ls[2] + ls[3];
  __syncthreads();
  const int len = len_sh;

  if (wid == 0) {
    const int ii = (sl < Lc) ? sl : 0;
    float alpha = (sl == START) ? 0.f : NEGC;
#pragma unroll 1
    for (int c = 0; c < NCH; ++c) {
      const float* M = Ms + c * 121;
      float terms[Lc];
      float m = -3.0e38f;
#pragma unroll
      for (int k = 0; k < Lc; k++) {
        const float ak = __shfl(alpha, k, 16);
        terms[k] = M[k * Lc + ii] + ak;
        m = fmaxf(m, terms[k]);
      }
      float s = 0.f;
#pragma unroll
      for (int k = 0; k < Lc; k++) s += exp2f((terms[k] - m) * LOG2E);
      const float anew = m + log2f(s) * LN2;
      alpha = (sl < Lc) ? anew : alpha;
    }
    float v = (sl < Lc) ? (alpha + trans[ENDL * Lc + sl]) : -3.0e38f;
    float mm = v;
#pragma unroll
    for (int off = 8; off >= 1; off >>= 1) mm = fmaxf(mm, __shfl_xor(mm, off, 16));
    float se = exp2f((v - mm) * LOG2E);
#pragma unroll
    for (int off = 8; off >= 1; off >>= 1) se += __shfl_xor(se, off, 16);
    if (lane == 0) norm_sh = mm + log2f(se) * LN2;
  } else {
    float u = 0.f;
    for (int t = tid - 64; t < Sc; t += 192)
      if (t < len) u += logits[((size_t)b * Sc + t) * NLc + labels[b * Sc + t]];
    for (int t = tid - 64; t <= Sc; t += 192) {
      if (t <= len) {
        const int cur = (t == 0) ? START : ((t - 1 < len) ? labels[b * Sc + t - 1] : ENDL);
        const int nxt = (t < len) ? labels[b * Sc + t] : ENDL;
        u += trans[nxt * Lc + cur];
      }
    }
#pragma unroll
    for (int off = 32; off >= 1; off >>= 1) u += __shfl_down(u, off);
    if (lane == 0) fs[wid] = u;
  }
  __syncthreads();

  if (tid == 0) {
    const float pb = fs[1] + fs[2] + fs[3] - norm_sh;
    __hip_atomic_store(&part[b], pb, __ATOMIC_RELEASE, __HIP_MEMORY_SCOPE_AGENT);
    const unsigned old = __hip_atomic_fetch_add(cnt, 1u, __ATOMIC_ACQ_REL,
                                                __HIP_MEMORY_SCOPE_AGENT);
    do_final = (old == (unsigned)(Bc - 1)) ? 1 : 0;
  }
  __syncthreads();
  if (do_final && wid == 0) {
    float v = __hip_atomic_load(&part[lane], __ATOMIC_RELAXED,
                                __HIP_MEMORY_SCOPE_AGENT);
#pragma unroll
    for (int off = 32; off >= 1; off >>= 1) v += __shfl_xor(v, off);
    if (lane == 0) out[0] = -v * (1.0f / Bc);
  }
}

extern "C" void kernel_launch(void* const* d_in, const int* in_sizes, int n_in,
                              void* d_out, int out_size, void* d_ws, size_t ws_size,
                              hipStream_t stream)
{
  const float* x      = (const float*)d_in[0];
  const int*   mask   = (const int*)d_in[1];
  const int*   labels = (const int*)d_in[2];
  const float* W      = (const float*)d_in[3];
  const float* bias   = (const float*)d_in[4];
  const float* trans  = (const float*)d_in[5];
  float* out = (float*)d_out;
  float* ws  = (float*)d_ws;

  float*    ws_logits = ws;                                  // B*S*NL floats
  float*    ws_M      = ws_logits + (size_t)Bc * Sc * NLc;   // B*NCH*121 floats
  float*    ws_part   = ws_M + (size_t)Bc * NCH * 121;       // B floats
  unsigned* ws_cnt    = (unsigned*)(ws_part + Bc);           // 1 uint

  hipLaunchKernelGGL(k_logits, dim3(512), dim3(256), 0, stream, x, W, bias, ws_logits);
  hipLaunchKernelGGL(k_chunk,  dim3(Bc * NCH), dim3(64), 0, stream, ws_logits, mask, trans, ws_M, ws_cnt);
  hipLaunchKernelGGL(k_batch,  dim3(Bc), dim3(256), 0, stream, ws_logits, mask, labels, trans, ws_M, ws_part, ws_cnt, out);
}

// Round 9
// 62.987 us; speedup vs baseline: 1.1104x; 1.0149x over previous
//
#include <hip/hip_runtime.h>

#define Bc 64
#define Sc 512
#define Dc 768
#define NLc 9
#define Lc 11
#define START (Lc-2)
#define ENDL (Lc-1)
#define NEGC -10000.0f
#define LOG2E 1.4426950408889634f
#define LN2 0.6931471805599453f
#define CHUNK 16
#define NCH (Sc / CHUNK)   // 32
#define WROW 776           // padded bf16 row stride (768+8 shorts): W reads 2-way (free)

#define ROWS 64            // rows per k_logits block
#define KC 96              // floats per K-chunk (3 MFMA k-steps)
#define NKC 8              // 768/96
#define XROW_B 384         // bytes per row in x LDS buffer
#define STG 6              // global_load_lds issues per thread per chunk (24KB/256/16)

typedef __attribute__((ext_vector_type(8))) short s16x8;   // 8 bf16 (4 VGPRs)
typedef __attribute__((ext_vector_type(4))) float f32x4;   // 4 fp32 acc

union U4 { float4 f; unsigned int u[4]; };
union R8 { unsigned int w[4]; s16x8 v; };

// pack 8 fp32 -> 8 bf16 (truncation; identical to R8 -> bit-identical logits)
static __device__ __forceinline__ s16x8 pack8(float4 lo, float4 hi) {
  U4 L, H; L.f = lo; H.f = hi;
  R8 r;
  r.w[0] = (L.u[1] & 0xFFFF0000u) | (L.u[0] >> 16);
  r.w[1] = (L.u[3] & 0xFFFF0000u) | (L.u[2] >> 16);
  r.w[2] = (H.u[1] & 0xFFFF0000u) | (H.u[0] >> 16);
  r.w[3] = (H.u[3] & 0xFFFF0000u) | (H.u[2] >> 16);
  return r.v;
}

// K1 (MFMA + global_load_lds DMA staging):
// R8 post-mortem: per-lane global loads cap at ~6.8 GB/s/CU (outstanding-miss
// limit on the vector-load return path) across ALL schedules. Route x through
// the async DMA path instead: 8 K-chunks of [64 rows x 96 floats] staged into
// double-buffered LDS via width-16 global_load_lds, counted vmcnt(6) (T4:
// never drain in the loop), raw s_barrier. x LDS layout XOR-swizzled via
// pre-swizzled GLOBAL source + swizzled read (rule #21): byte ^= (row&7)<<4
// -> A-frag reads 2-way (free). MFMA math identical to R8.
__global__ __launch_bounds__(256, 2) void k_logits(const float* __restrict__ x,
    const float* __restrict__ W, const float* __restrict__ bias,
    float* __restrict__ out)
{
  __shared__ float Xb[2][ROWS * KC];        // 2 x 24576 B
  __shared__ unsigned short Wb[16][WROW];   // 24832 B   (total 73984 B -> 2 blocks/CU)

  const int tid = threadIdx.x;
  const int Rb  = blockIdx.x * ROWS;

  // ---- issue chunk 0 and 1 DMA first (in flight during W staging) ----
#define STAGE(c, p)                                                            \
  {                                                                            \
    _Pragma("unroll")                                                          \
    for (int u = 0; u < STG; ++u) {                                            \
      const int lo   = (u * 256 + tid) * 16;       /* byte offset in buffer */ \
      const int row  = lo / XROW_B;                                            \
      const int colb = lo % XROW_B;                                            \
      const int scol = colb ^ ((row & 7) << 4);    /* inverse swizzle (invol.)*/\
      const float* gp = x + (size_t)(Rb + row) * Dc + (c) * KC + (scol >> 2);  \
      __builtin_amdgcn_global_load_lds(gp, &Xb[p][0] + (lo >> 2), 16, 0, 0);   \
    }                                                                          \
  }
  STAGE(0, 0)
  STAGE(1, 1)

  // ---- stage W as bf16 (rows 9..15 zero) ----
  for (int i = tid; i < 16 * 384; i += 256) {
    const int r = i / 384, c = i % 384;     // c = u32 word (2 bf16)
    unsigned int w = 0u;
    if (r < NLc) {
      U4 t; t.f.x = W[r * Dc + 2 * c]; t.f.y = W[r * Dc + 2 * c + 1];
      w = (t.u[1] & 0xFFFF0000u) | (t.u[0] >> 16);
    }
    *reinterpret_cast<unsigned int*>(&Wb[r][2 * c]) = w;
  }
  __syncthreads();   // drains vmcnt(0): W ready AND chunks 0,1 landed

  const int lane = tid & 63;
  const int w    = tid >> 6;                // wave 0..3 -> rows [w*16, w*16+16)
  const int j    = lane & 15;               // A row within tile / B col (label)
  const int kg   = lane >> 4;               // k-group 0..3
  const int sw   = (j & 7) << 4;            // read-side swizzle (byte)

  f32x4 acc = {0.f, 0.f, 0.f, 0.f};

#pragma unroll
  for (int c = 0; c < NKC; ++c) {
    const int p = c & 1;
    asm volatile("" ::: "memory");          // no hoisting reads above barrier
    // ---- compute chunk c: 3 MFMA k-steps ----
    const char* xrow = reinterpret_cast<const char*>(&Xb[p][(w * 16 + j) * KC]);
#pragma unroll
    for (int s = 0; s < 3; ++s) {
      const int cb0 = (s * 128 + kg * 32) ^ sw;
      const float4 a0 = *reinterpret_cast<const float4*>(xrow + cb0);
      const float4 a1 = *reinterpret_cast<const float4*>(xrow + (cb0 ^ 16));
      const s16x8 afrag = pack8(a0, a1);
      const s16x8 bfrag = *reinterpret_cast<const s16x8*>(&Wb[j][c * KC + s * 32 + kg * 8]);
      acc = __builtin_amdgcn_mfma_f32_16x16x32_bf16(afrag, bfrag, acc, 0, 0, 0);
    }
    __builtin_amdgcn_s_barrier();           // all waves done reading Xb[p]
    if (c + 2 < NKC) {
      STAGE(c + 2, p)                       // refill the buffer just consumed
      asm volatile("s_waitcnt vmcnt(6)" ::: "memory");  // chunk c+1 landed; c+2 in flight
    } else {
      asm volatile("s_waitcnt vmcnt(0)" ::: "memory");  // epilogue drain
    }
    __builtin_amdgcn_sched_barrier(0);
    __builtin_amdgcn_s_barrier();           // publish chunk c+1
  }
#undef STAGE

  // C/D store (m89-verified layout, identical to R8): col=j(label), row=kg*4+r
  if (j < NLc) {
    const float bb = bias[j];
    const int R = Rb + w * 16;
#pragma unroll
    for (int r = 0; r < 4; ++r) {
      const int row = R + kg * 4 + r;
      out[(size_t)row * NLc + j] = acc[r] + bb;
    }
  }
}

// Phase 1: per (batch, chunk) compute the 11x11 log-semiring transfer matrix.
// Storage: Mout[(b*NCH+c)*121 + j*11 + i] = M[i][j] (exit i, enter j).
// Also zeroes the k_batch completion counter (block 0) each call.
__global__ __launch_bounds__(64) void k_chunk(const float* __restrict__ logits,
    const int* __restrict__ mask, const float* __restrict__ trans,
    float* __restrict__ Mout, unsigned* __restrict__ cnt)
{
  if (blockIdx.x == 0 && threadIdx.x == 0) cnt[0] = 0u;
  const int b = blockIdx.x / NCH;
  const int c = blockIdx.x % NCH;
  const int lane = threadIdx.x;
  __shared__ float Mbuf[2][121];
  __shared__ float Llog[CHUNK][NLc];

  int len = 0;
  for (int t = lane; t < Sc; t += 64) len += mask[b * Sc + t];
#pragma unroll
  for (int off = 32; off >= 1; off >>= 1) len += __shfl_xor(len, off);

  for (int i = lane; i < CHUNK * NLc; i += 64) {
    const int t = i / NLc, l = i % NLc;
    Llog[t][l] = logits[((size_t)b * Sc + c * CHUNK + t) * NLc + l];
  }
  for (int e = lane; e < 121; e += 64) {
    const int i = e % Lc, j = e / Lc;
    Mbuf[0][e] = (i == j) ? 0.f : NEGC;
  }
  const int e1 = lane;          const bool v1 = (e1 < 121);
  const int e2 = lane + 64;     const bool v2 = (e2 < 121);
  const int i1 = v1 ? (e1 % Lc) : 0, j1 = v1 ? (e1 / Lc) : 0;
  const int i2 = v2 ? (e2 % Lc) : 0, j2 = v2 ? (e2 / Lc) : 0;
  float trow1[Lc], trow2[Lc];
#pragma unroll
  for (int k = 0; k < Lc; k++) {
    trow1[k] = trans[i1 * Lc + k];
    trow2[k] = trans[i2 * Lc + k];
  }
  __syncthreads();

  int p = 0;
  for (int t = 0; t < CHUNK; ++t) {
    const int tg = c * CHUNK + t;
    if (tg < len) {   // uniform across block
      const float lg1 = (i1 < NLc) ? Llog[t][i1] : NEGC;
      const float lg2 = (i2 < NLc) ? Llog[t][i2] : NEGC;
      float terms[Lc];
      float m1 = -3.0e38f;
#pragma unroll
      for (int k = 0; k < Lc; k++) {
        terms[k] = trow1[k] + Mbuf[p][j1 * Lc + k];
        m1 = fmaxf(m1, terms[k]);
      }
      float s1 = 0.f;
#pragma unroll
      for (int k = 0; k < Lc; k++) s1 += exp2f((terms[k] - m1) * LOG2E);
      const float n1 = lg1 + m1 + log2f(s1) * LN2;
      float m2 = -3.0e38f;
#pragma unroll
      for (int k = 0; k < Lc; k++) {
        terms[k] = trow2[k] + Mbuf[p][j2 * Lc + k];
        m2 = fmaxf(m2, terms[k]);
      }
      float s2 = 0.f;
#pragma unroll
      for (int k = 0; k < Lc; k++) s2 += exp2f((terms[k] - m2) * LOG2E);
      const float n2 = lg2 + m2 + log2f(s2) * LN2;
      if (v1) Mbuf[p ^ 1][e1] = n1;
      if (v2) Mbuf[p ^ 1][e2] = n2;
      p ^= 1;
    }
    __syncthreads();
  }
  for (int e = lane; e < 121; e += 64)
    Mout[((size_t)b * NCH + c) * 121 + e] = Mbuf[p][e];
}

// K_batch: per batch -- wave 0 runs the 32-step combine (norm), waves 1-3 do
// unary+binary gathers concurrently; then part[b] = u - norm; the last block
// to finish sums all parts and writes the loss (agent-scope atomics, G16).
__global__ __launch_bounds__(256) void k_batch(const float* __restrict__ logits,
    const int* __restrict__ mask, const int* __restrict__ labels,
    const float* __restrict__ trans, const float* __restrict__ Min,
    float* __restrict__ part, unsigned* __restrict__ cnt,
    float* __restrict__ out)
{
  const int b = blockIdx.x;
  const int tid = threadIdx.x;
  const int wid = tid >> 6;
  const int lane = tid & 63;
  const int sl = lane & 15;
  __shared__ float Ms[NCH * 121];
  __shared__ int   ls[4];
  __shared__ float fs[4];
  __shared__ int   len_sh;
  __shared__ float norm_sh;
  __shared__ int   do_final;

  {
    const float4* src = reinterpret_cast<const float4*>(Min + (size_t)b * NCH * 121);
    for (int i = tid; i < (NCH * 121) / 4; i += 256)
      reinterpret_cast<float4*>(Ms)[i] = src[i];
  }
  int lp = 0;
  for (int t = tid; t < Sc; t += 256) lp += mask[b * Sc + t];
#pragma unroll
  for (int off = 32; off >= 1; off >>= 1) lp += __shfl_down(lp, off);
  if (lane == 0) ls[wid] = lp;
  __syncthreads();
  if (tid == 0) len_sh = ls[0] + ls[1] + ls[2] + ls[3];
  __syncthreads();
  const int len = len_sh;

  if (wid == 0) {
    const int ii = (sl < Lc) ? sl : 0;
    float alpha = (sl == START) ? 0.f : NEGC;
#pragma unroll 1
    for (int c = 0; c < NCH; ++c) {
      const float* M = Ms + c * 121;
      float terms[Lc];
      float m = -3.0e38f;
#pragma unroll
      for (int k = 0; k < Lc; k++) {
        const float ak = __shfl(alpha, k, 16);
        terms[k] = M[k * Lc + ii] + ak;
        m = fmaxf(m, terms[k]);
      }
      float s = 0.f;
#pragma unroll
      for (int k = 0; k < Lc; k++) s += exp2f((terms[k] - m) * LOG2E);
      const float anew = m + log2f(s) * LN2;
      alpha = (sl < Lc) ? anew : alpha;
    }
    float v = (sl < Lc) ? (alpha + trans[ENDL * Lc + sl]) : -3.0e38f;
    float mm = v;
#pragma unroll
    for (int off = 8; off >= 1; off >>= 1) mm = fmaxf(mm, __shfl_xor(mm, off, 16));
    float se = exp2f((v - mm) * LOG2E);
#pragma unroll
    for (int off = 8; off >= 1; off >>= 1) se += __shfl_xor(se, off, 16);
    if (lane == 0) norm_sh = mm + log2f(se) * LN2;
  } else {
    float u = 0.f;
    for (int t = tid - 64; t < Sc; t += 192)
      if (t < len) u += logits[((size_t)b * Sc + t) * NLc + labels[b * Sc + t]];
    for (int t = tid - 64; t <= Sc; t += 192) {
      if (t <= len) {
        const int cur = (t == 0) ? START : ((t - 1 < len) ? labels[b * Sc + t - 1] : ENDL);
        const int nxt = (t < len) ? labels[b * Sc + t] : ENDL;
        u += trans[nxt * Lc + cur];
      }
    }
#pragma unroll
    for (int off = 32; off >= 1; off >>= 1) u += __shfl_down(u, off);
    if (lane == 0) fs[wid] = u;
  }
  __syncthreads();

  if (tid == 0) {
    const float pb = fs[1] + fs[2] + fs[3] - norm_sh;
    __hip_atomic_store(&part[b], pb, __ATOMIC_RELEASE, __HIP_MEMORY_SCOPE_AGENT);
    const unsigned old = __hip_atomic_fetch_add(cnt, 1u, __ATOMIC_ACQ_REL,
                                                __HIP_MEMORY_SCOPE_AGENT);
    do_final = (old == (unsigned)(Bc - 1)) ? 1 : 0;
  }
  __syncthreads();
  if (do_final && wid == 0) {
    float v = __hip_atomic_load(&part[lane], __ATOMIC_RELAXED,
                                __HIP_MEMORY_SCOPE_AGENT);
#pragma unroll
    for (int off = 32; off >= 1; off >>= 1) v += __shfl_xor(v, off);
    if (lane == 0) out[0] = -v * (1.0f / Bc);
  }
}

extern "C" void kernel_launch(void* const* d_in, const int* in_sizes, int n_in,
                              void* d_out, int out_size, void* d_ws, size_t ws_size,
                              hipStream_t stream)
{
  const float* x      = (const float*)d_in[0];
  const int*   mask   = (const int*)d_in[1];
  const int*   labels = (const int*)d_in[2];
  const float* W      = (const float*)d_in[3];
  const float* bias   = (const float*)d_in[4];
  const float* trans  = (const float*)d_in[5];
  float* out = (float*)d_out;
  float* ws  = (float*)d_ws;

  float*    ws_logits = ws;                                  // B*S*NL floats
  float*    ws_M      = ws_logits + (size_t)Bc * Sc * NLc;   // B*NCH*121 floats
  float*    ws_part   = ws_M + (size_t)Bc * NCH * 121;       // B floats
  unsigned* ws_cnt    = (unsigned*)(ws_part + Bc);           // 1 uint

  hipLaunchKernelGGL(k_logits, dim3(512), dim3(256), 0, stream, x, W, bias, ws_logits);
  hipLaunchKernelGGL(k_chunk,  dim3(Bc * NCH), dim3(64), 0, stream, ws_logits, mask, trans, ws_M, ws_cnt);
  hipLaunchKernelGGL(k_batch,  dim3(Bc), dim3(256), 0, stream, ws_logits, mask, labels, trans, ws_M, ws_part, ws_cnt, out);
}